// Round 1
// baseline (421.297 us; speedup 1.0000x reference)
//
#include <hip/hip_runtime.h>
#include <math.h>

#define T 2048
#define HIDDEN 2048
#define NH 16
#define NKV 4
#define HD 128
#define QKV_N 3072   // (16 + 2*4) * 128
#define Q_SIZE 2048  // 16*128
#define KV_SIZE 512  // 4*128

typedef __attribute__((ext_vector_type(8))) short short8;
typedef __attribute__((ext_vector_type(4))) float floatx4;

__device__ __forceinline__ unsigned short f2bf(float f) {
    union { float f; unsigned int u; } v; v.f = f;
    unsigned int u = v.u;
    u += 0x7fffu + ((u >> 16) & 1u);   // round-to-nearest-even
    return (unsigned short)(u >> 16);
}
__device__ __forceinline__ float bf2f(unsigned short h) {
    union { unsigned int u; float f; } v; v.u = ((unsigned int)h) << 16;
    return v.f;
}

// ---------------- cos/sin tables (mrope sectioning) ----------------
// cos_sec[t][j] = cos(pos[row(j)][t] * theta^(-j/64)),
// row(j) = 0 if j>=44 else (2 if j odd else 1)
__global__ void prep_cossin(const int* __restrict__ positions,
                            float* __restrict__ cosT, float* __restrict__ sinT) {
    int t = blockIdx.x;
    int j = threadIdx.x;           // 0..63
    int row = (j >= 44) ? 0 : ((j & 1) ? 2 : 1);
    int pos = positions[row * T + t];
    double invf = pow(500000.0, -(double)j / 64.0);
    double ang = (double)pos * invf;
    cosT[t * 64 + j] = (float)cos(ang);
    sinT[t * 64 + j] = (float)sin(ang);
}

// ---------------- fp32 -> bf16 convert ----------------
__global__ __launch_bounds__(256) void convert_f32_bf16(const float* __restrict__ in,
                                                        unsigned short* __restrict__ out, int n) {
    int i = (blockIdx.x * 256 + threadIdx.x) * 4;
    if (i + 3 < n) {
        float4 v = *(const float4*)(in + i);
        out[i]     = f2bf(v.x);
        out[i + 1] = f2bf(v.y);
        out[i + 2] = f2bf(v.z);
        out[i + 3] = f2bf(v.w);
    }
}

// ---------------- transpose fp32 -> bf16 : out[c][r] = in[r][c] ----------------
__global__ __launch_bounds__(256) void transpose_f32_bf16(const float* __restrict__ in,
                                                          unsigned short* __restrict__ out,
                                                          int R, int C) {
    __shared__ float tile[32][33];
    int tx = threadIdx.x, ty = threadIdx.y;          // (32,8)
    int c0 = blockIdx.x * 32, r0 = blockIdx.y * 32;
#pragma unroll
    for (int i = 0; i < 4; ++i)
        tile[ty + i * 8][tx] = in[(long)(r0 + ty + i * 8) * C + c0 + tx];
    __syncthreads();
#pragma unroll
    for (int i = 0; i < 4; ++i)
        out[(long)(c0 + ty + i * 8) * R + r0 + tx] = f2bf(tile[tx][ty + i * 8]);
}

// ---------------- transpose bf16 (batched over z) ----------------
__global__ __launch_bounds__(256) void transpose_bf16(const unsigned short* __restrict__ in,
                                                      unsigned short* __restrict__ out,
                                                      int R, int C) {
    __shared__ unsigned short tile[32][33];
    long zo = (long)blockIdx.z * R * C;
    in += zo; out += zo;
    int tx = threadIdx.x, ty = threadIdx.y;
    int c0 = blockIdx.x * 32, r0 = blockIdx.y * 32;
#pragma unroll
    for (int i = 0; i < 4; ++i)
        tile[ty + i * 8][tx] = in[(long)(r0 + ty + i * 8) * C + c0 + tx];
    __syncthreads();
#pragma unroll
    for (int i = 0; i < 4; ++i)
        out[(long)(c0 + ty + i * 8) * R + r0 + tx] = tile[tx][ty + i * 8];
}

// ---------------- rope + split qkv -> q_bf, k_bf, v_bf ----------------
__global__ __launch_bounds__(256) void rope_split(const float* __restrict__ qkv,
                                                  const float* __restrict__ cosT,
                                                  const float* __restrict__ sinT,
                                                  unsigned short* __restrict__ qb,
                                                  unsigned short* __restrict__ kb,
                                                  unsigned short* __restrict__ vb) {
    int t = blockIdx.x, tid = threadIdx.x;
    const float* row = qkv + (long)t * QKV_N;
    const float* ct = cosT + t * 64;
    const float* st = sinT + t * 64;
    // Q: 16 heads x 64 pairs
    for (int i = tid; i < NH * 64; i += 256) {
        int h = i >> 6, j = i & 63;
        float c = ct[j], s = st[j];
        float x1 = row[h * HD + 2 * j], x2 = row[h * HD + 2 * j + 1];
        qb[(long)t * Q_SIZE + h * HD + 2 * j]     = f2bf(x1 * c - x2 * s);
        qb[(long)t * Q_SIZE + h * HD + 2 * j + 1] = f2bf(x2 * c + x1 * s);
    }
    // K: 4 kv heads x 64 pairs = 256 (one per thread)
    {
        int i = tid;
        int g = i >> 6, j = i & 63;
        float c = ct[j], s = st[j];
        float x1 = row[Q_SIZE + g * HD + 2 * j], x2 = row[Q_SIZE + g * HD + 2 * j + 1];
        kb[(long)t * KV_SIZE + g * HD + 2 * j]     = f2bf(x1 * c - x2 * s);
        kb[(long)t * KV_SIZE + g * HD + 2 * j + 1] = f2bf(x2 * c + x1 * s);
    }
    // V: no rope; store g-major [g][t][d]
    for (int i = tid; i < KV_SIZE; i += 256) {
        int g = i >> 7, d = i & 127;
        vb[((long)g * T + t) * HD + d] = f2bf(row[Q_SIZE + KV_SIZE + g * HD + d]);
    }
}

// ---------------- GEMM: C[z] = A[z] (MxK) * B[z>>bShift]^T (NxK), bf16 in, MFMA ----------------
// 64x64 tile, 4 waves, each wave: 16 rows x 64 cols via 4x mfma_f32_16x16x32_bf16
__global__ __launch_bounds__(256) void gemm_bt(const unsigned short* __restrict__ A, long aStride, int lda,
                                               const unsigned short* __restrict__ B, long bStride, int bShift, int ldb,
                                               void* __restrict__ Cv, long cStride, int ldc,
                                               int K, float scale, int writeBf16) {
    __shared__ __align__(16) unsigned short As[64][40];
    __shared__ __align__(16) unsigned short Bs[64][40];
    const int tid = threadIdx.x;
    const int z = blockIdx.z;
    const unsigned short* Ab = A + (long)z * aStride + (long)(blockIdx.x * 64) * lda;
    const unsigned short* Bb = B + (long)(z >> bShift) * bStride + (long)(blockIdx.y * 64) * ldb;

    const int sr = tid >> 2;          // 0..63  staging row
    const int sc = (tid & 3) * 8;     // 0,8,16,24 staging col (8 bf16 = 16B)

    const int wv = tid >> 6;          // wave 0..3
    const int lane = tid & 63;
    const int m = lane & 15;
    const int qd = lane >> 4;

    floatx4 acc[4];
#pragma unroll
    for (int c = 0; c < 4; ++c) acc[c] = (floatx4){0.f, 0.f, 0.f, 0.f};

    for (int k0 = 0; k0 < K; k0 += 32) {
        __syncthreads();
        *(uint4*)&As[sr][sc] = *(const uint4*)(Ab + (long)sr * lda + k0 + sc);
        *(uint4*)&Bs[sr][sc] = *(const uint4*)(Bb + (long)sr * ldb + k0 + sc);
        __syncthreads();
        short8 a = *(const short8*)&As[wv * 16 + m][qd * 8];
#pragma unroll
        for (int c = 0; c < 4; ++c) {
            short8 b = *(const short8*)&Bs[c * 16 + m][qd * 8];
            acc[c] = __builtin_amdgcn_mfma_f32_16x16x32_bf16(a, b, acc[c], 0, 0, 0);
        }
    }

    const long crow0 = (long)blockIdx.x * 64 + wv * 16 + qd * 4;
    const int ccol0 = blockIdx.y * 64;
    if (writeBf16) {
        unsigned short* Cb = (unsigned short*)Cv + (long)z * cStride;
#pragma unroll
        for (int c = 0; c < 4; ++c)
#pragma unroll
            for (int r = 0; r < 4; ++r)
                Cb[(crow0 + r) * ldc + ccol0 + c * 16 + m] = f2bf(acc[c][r] * scale);
    } else {
        float* Cf = (float*)Cv + (long)z * cStride;
#pragma unroll
        for (int c = 0; c < 4; ++c)
#pragma unroll
            for (int r = 0; r < 4; ++r)
                Cf[(crow0 + r) * ldc + ccol0 + c * 16 + m] = acc[c][r] * scale;
    }
}

// ---------------- causal softmax, in-place on bf16 scores -> P ----------------
__global__ __launch_bounds__(256) void softmax_causal(unsigned short* __restrict__ P) {
    int t = blockIdx.x, h = blockIdx.y, tid = threadIdx.x;
    unsigned short* row = P + ((long)h * T + t) * T;
    int len = t + 1;
    __shared__ float red[256];
    float m = -1e30f;
    for (int j = tid; j < len; j += 256) m = fmaxf(m, bf2f(row[j]));
    red[tid] = m; __syncthreads();
    for (int s = 128; s > 0; s >>= 1) { if (tid < s) red[tid] = fmaxf(red[tid], red[tid + s]); __syncthreads(); }
    float M = red[0]; __syncthreads();
    float sum = 0.f;
    for (int j = tid; j < len; j += 256) sum += __expf(bf2f(row[j]) - M);
    red[tid] = sum; __syncthreads();
    for (int s = 128; s > 0; s >>= 1) { if (tid < s) red[tid] += red[tid + s]; __syncthreads(); }
    float inv = 1.f / red[0];
    for (int j = tid; j < T; j += 256) {
        float v = (j < len) ? __expf(bf2f(row[j]) - M) * inv : 0.f;
        row[j] = f2bf(v);
    }
}

extern "C" void kernel_launch(void* const* d_in, const int* in_sizes, int n_in,
                              void* d_out, int out_size, void* d_ws, size_t ws_size,
                              hipStream_t stream) {
    const int* positions = (const int*)d_in[0];
    const float* hidden  = (const float*)d_in[1];
    const float* w_qkv   = (const float*)d_in[2];
    const float* w_o     = (const float*)d_in[3];
    float* out = (float*)d_out;

    char* p = (char*)d_ws;
    auto alloc = [&](size_t bytes) { char* r = p; p += (bytes + 255) & ~(size_t)255; return r; };
    float* cosT = (float*)alloc((size_t)T * 64 * 4);
    float* sinT = (float*)alloc((size_t)T * 64 * 4);
    float* qkv  = (float*)alloc((size_t)T * QKV_N * 4);
    unsigned short* hb  = (unsigned short*)alloc((size_t)T * HIDDEN * 2);
    unsigned short* wqt = (unsigned short*)alloc((size_t)QKV_N * HIDDEN * 2);
    unsigned short* wot = (unsigned short*)alloc((size_t)HIDDEN * HIDDEN * 2);
    unsigned short* qb  = (unsigned short*)alloc((size_t)T * Q_SIZE * 2);
    unsigned short* kb  = (unsigned short*)alloc((size_t)T * KV_SIZE * 2);
    unsigned short* vb  = (unsigned short*)alloc((size_t)T * KV_SIZE * 2);
    unsigned short* vt  = (unsigned short*)alloc((size_t)T * KV_SIZE * 2);
    unsigned short* ab  = (unsigned short*)alloc((size_t)T * Q_SIZE * 2);
    unsigned short* Pb  = (unsigned short*)alloc((size_t)NH * T * T * 2);

    dim3 tb(32, 8);
    prep_cossin<<<T, 64, 0, stream>>>(positions, cosT, sinT);
    convert_f32_bf16<<<(T * HIDDEN) / 1024, 256, 0, stream>>>(hidden, hb, T * HIDDEN);
    transpose_f32_bf16<<<dim3(QKV_N / 32, HIDDEN / 32), tb, 0, stream>>>(w_qkv, wqt, HIDDEN, QKV_N);
    transpose_f32_bf16<<<dim3(HIDDEN / 32, HIDDEN / 32), tb, 0, stream>>>(w_o, wot, HIDDEN, HIDDEN);
    // qkv = hidden @ w_qkv   (fp32 out)
    gemm_bt<<<dim3(T / 64, QKV_N / 64, 1), 256, 0, stream>>>(hb, 0, HIDDEN, wqt, 0, 0, HIDDEN,
                                                             qkv, 0, QKV_N, HIDDEN, 1.0f, 0);
    rope_split<<<T, 256, 0, stream>>>(qkv, cosT, sinT, qb, kb, vb);
    transpose_bf16<<<dim3(HD / 32, T / 32, NKV), tb, 0, stream>>>(vb, vt, T, HD);
    // scores[h] = scale * Q_h K_h^T  (bf16 out into Pb)
    gemm_bt<<<dim3(T / 64, T / 64, NH), 256, 0, stream>>>(qb, 128, Q_SIZE, kb, 128, 2, KV_SIZE,
                                                          Pb, (long)T * T, T, HD, 0.08838834764831845f, 1);
    softmax_causal<<<dim3(T, NH), 256, 0, stream>>>(Pb);
    // attn_out[h] = P_h V_h
    gemm_bt<<<dim3(T / 64, HD / 64, NH), 256, 0, stream>>>(Pb, (long)T * T, T, vt, (long)HD * T, 2, T,
                                                           ab, 128, Q_SIZE, T, 1.0f, 1);
    // out = attn @ w_o  (fp32 out)
    gemm_bt<<<dim3(T / 64, HIDDEN / 64, 1), 256, 0, stream>>>(ab, 0, Q_SIZE, wot, 0, 0, HIDDEN,
                                                              out, 0, HIDDEN, Q_SIZE, 1.0f, 0);
}

// Round 2
// 336.218 us; speedup vs baseline: 1.2531x; 1.2531x over previous
//
#include <hip/hip_runtime.h>
#include <math.h>

#define T 2048
#define HIDDEN 2048
#define NH 16
#define NKV 4
#define HD 128
#define QKV_N 3072   // (16 + 2*4) * 128
#define Q_SIZE 2048  // 16*128
#define KV_SIZE 512  // 4*128

typedef __attribute__((ext_vector_type(8))) short short8;
typedef __attribute__((ext_vector_type(4))) float floatx4;

__device__ __forceinline__ unsigned short f2bf(float f) {
    union { float f; unsigned int u; } v; v.f = f;
    unsigned int u = v.u;
    u += 0x7fffu + ((u >> 16) & 1u);   // round-to-nearest-even
    return (unsigned short)(u >> 16);
}
__device__ __forceinline__ float bf2f(unsigned short h) {
    union { unsigned int u; float f; } v; v.u = ((unsigned int)h) << 16;
    return v.f;
}

// ---------------- cos/sin tables (mrope sectioning) ----------------
__global__ void prep_cossin(const int* __restrict__ positions,
                            float* __restrict__ cosT, float* __restrict__ sinT) {
    int t = blockIdx.x;
    int j = threadIdx.x;           // 0..63
    int row = (j >= 44) ? 0 : ((j & 1) ? 2 : 1);
    int pos = positions[row * T + t];
    double invf = pow(500000.0, -(double)j / 64.0);
    double ang = (double)pos * invf;
    cosT[t * 64 + j] = (float)cos(ang);
    sinT[t * 64 + j] = (float)sin(ang);
}

// ---------------- fp32 -> bf16 convert ----------------
__global__ __launch_bounds__(256) void convert_f32_bf16(const float* __restrict__ in,
                                                        unsigned short* __restrict__ out, int n) {
    int i = (blockIdx.x * 256 + threadIdx.x) * 4;
    if (i + 3 < n) {
        float4 v = *(const float4*)(in + i);
        out[i]     = f2bf(v.x);
        out[i + 1] = f2bf(v.y);
        out[i + 2] = f2bf(v.z);
        out[i + 3] = f2bf(v.w);
    }
}

// ---------------- transpose fp32 -> bf16 : out[c][r] = in[r][c] ----------------
__global__ __launch_bounds__(256) void transpose_f32_bf16(const float* __restrict__ in,
                                                          unsigned short* __restrict__ out,
                                                          int R, int C) {
    __shared__ float tile[32][33];
    int tx = threadIdx.x, ty = threadIdx.y;          // (32,8)
    int c0 = blockIdx.x * 32, r0 = blockIdx.y * 32;
#pragma unroll
    for (int i = 0; i < 4; ++i)
        tile[ty + i * 8][tx] = in[(long)(r0 + ty + i * 8) * C + c0 + tx];
    __syncthreads();
#pragma unroll
    for (int i = 0; i < 4; ++i)
        out[(long)(c0 + ty + i * 8) * R + r0 + tx] = f2bf(tile[tx][ty + i * 8]);
}

// ---------------- transpose bf16 (batched over z) ----------------
__global__ __launch_bounds__(256) void transpose_bf16(const unsigned short* __restrict__ in,
                                                      unsigned short* __restrict__ out,
                                                      int R, int C) {
    __shared__ unsigned short tile[32][33];
    long zo = (long)blockIdx.z * R * C;
    in += zo; out += zo;
    int tx = threadIdx.x, ty = threadIdx.y;
    int c0 = blockIdx.x * 32, r0 = blockIdx.y * 32;
#pragma unroll
    for (int i = 0; i < 4; ++i)
        tile[ty + i * 8][tx] = in[(long)(r0 + ty + i * 8) * C + c0 + tx];
    __syncthreads();
#pragma unroll
    for (int i = 0; i < 4; ++i)
        out[(long)(c0 + ty + i * 8) * R + r0 + tx] = tile[tx][ty + i * 8];
}

// ---------------- rope + split qkv -> q_bf, k_bf, v_bf ----------------
__global__ __launch_bounds__(256) void rope_split(const float* __restrict__ qkv,
                                                  const float* __restrict__ cosT,
                                                  const float* __restrict__ sinT,
                                                  unsigned short* __restrict__ qb,
                                                  unsigned short* __restrict__ kb,
                                                  unsigned short* __restrict__ vb) {
    int t = blockIdx.x, tid = threadIdx.x;
    const float* row = qkv + (long)t * QKV_N;
    const float* ct = cosT + t * 64;
    const float* st = sinT + t * 64;
    for (int i = tid; i < NH * 64; i += 256) {
        int h = i >> 6, j = i & 63;
        float c = ct[j], s = st[j];
        float x1 = row[h * HD + 2 * j], x2 = row[h * HD + 2 * j + 1];
        qb[(long)t * Q_SIZE + h * HD + 2 * j]     = f2bf(x1 * c - x2 * s);
        qb[(long)t * Q_SIZE + h * HD + 2 * j + 1] = f2bf(x2 * c + x1 * s);
    }
    {
        int i = tid;
        int g = i >> 6, j = i & 63;
        float c = ct[j], s = st[j];
        float x1 = row[Q_SIZE + g * HD + 2 * j], x2 = row[Q_SIZE + g * HD + 2 * j + 1];
        kb[(long)t * KV_SIZE + g * HD + 2 * j]     = f2bf(x1 * c - x2 * s);
        kb[(long)t * KV_SIZE + g * HD + 2 * j + 1] = f2bf(x2 * c + x1 * s);
    }
    for (int i = tid; i < KV_SIZE; i += 256) {
        int g = i >> 7, d = i & 127;
        vb[((long)g * T + t) * HD + d] = f2bf(row[Q_SIZE + KV_SIZE + g * HD + d]);
    }
}

// ---------------- GEMM: C[z] = A[z] (MxK) * B[z>>bShift]^T (NxK) ----------------
__global__ __launch_bounds__(256) void gemm_bt(const unsigned short* __restrict__ A, long aStride, int lda,
                                               const unsigned short* __restrict__ B, long bStride, int bShift, int ldb,
                                               void* __restrict__ Cv, long cStride, int ldc,
                                               int K, float scale, int writeBf16) {
    __shared__ __align__(16) unsigned short As[64][40];
    __shared__ __align__(16) unsigned short Bs[64][40];
    const int tid = threadIdx.x;
    const int z = blockIdx.z;
    const unsigned short* Ab = A + (long)z * aStride + (long)(blockIdx.x * 64) * lda;
    const unsigned short* Bb = B + (long)(z >> bShift) * bStride + (long)(blockIdx.y * 64) * ldb;

    const int sr = tid >> 2;
    const int sc = (tid & 3) * 8;

    const int wv = tid >> 6;
    const int lane = tid & 63;
    const int m = lane & 15;
    const int qd = lane >> 4;

    floatx4 acc[4];
#pragma unroll
    for (int c = 0; c < 4; ++c) acc[c] = (floatx4){0.f, 0.f, 0.f, 0.f};

    for (int k0 = 0; k0 < K; k0 += 32) {
        __syncthreads();
        *(uint4*)&As[sr][sc] = *(const uint4*)(Ab + (long)sr * lda + k0 + sc);
        *(uint4*)&Bs[sr][sc] = *(const uint4*)(Bb + (long)sr * ldb + k0 + sc);
        __syncthreads();
        short8 a = *(const short8*)&As[wv * 16 + m][qd * 8];
#pragma unroll
        for (int c = 0; c < 4; ++c) {
            short8 b = *(const short8*)&Bs[c * 16 + m][qd * 8];
            acc[c] = __builtin_amdgcn_mfma_f32_16x16x32_bf16(a, b, acc[c], 0, 0, 0);
        }
    }

    const long crow0 = (long)blockIdx.x * 64 + wv * 16 + qd * 4;
    const int ccol0 = blockIdx.y * 64;
    if (writeBf16) {
        unsigned short* Cb = (unsigned short*)Cv + (long)z * cStride;
#pragma unroll
        for (int c = 0; c < 4; ++c)
#pragma unroll
            for (int r = 0; r < 4; ++r)
                Cb[(crow0 + r) * ldc + ccol0 + c * 16 + m] = f2bf(acc[c][r] * scale);
    } else {
        float* Cf = (float*)Cv + (long)z * cStride;
#pragma unroll
        for (int c = 0; c < 4; ++c)
#pragma unroll
            for (int r = 0; r < 4; ++r)
                Cf[(crow0 + r) * ldc + ccol0 + c * 16 + m] = acc[c][r] * scale;
    }
}

// ---------------- flash attention: out[t][h*128+d], causal, online softmax ----------------
// grid (32, 1, NH), block 256. Each block: 64 Q-rows of one head.
// LDS layout (shorts): Ks[64][136] @0, Vts[128][72] @8704, Qs[64][136]/Ps[4][16][72] @17920
#define KS(r, c)   smem[(r) * 136 + (c)]
#define VTS(r, c)  smem[8704 + (r) * 72 + (c)]
#define QS(r, c)   smem[17920 + (r) * 136 + (c)]
#define PS(w, r, c) smem[17920 + ((w) * 16 + (r)) * 72 + (c)]

__global__ __launch_bounds__(256) void flash_attn(const unsigned short* __restrict__ qb,
                                                  const unsigned short* __restrict__ kb,
                                                  const unsigned short* __restrict__ vt,
                                                  unsigned short* __restrict__ ab) {
    __shared__ __align__(16) unsigned short smem[26624];
    const int tid = threadIdx.x;
    const int h = blockIdx.z;
    const int g = h >> 2;
    // heavy/light pairing: blocks 2c,2c+1 -> q-blocks {c, 31-c}
    const int bxx = blockIdx.x;
    const int qblk = (bxx & 1) ? (31 - (bxx >> 1)) : (bxx >> 1);
    const int q0 = qblk * 64;

    const int wv = tid >> 6;
    const int lane = tid & 63;
    const int m = lane & 15;
    const int qd = lane >> 4;

    // stage Q tile (64x128)
    {
        int row = tid >> 2, colb = (tid & 3) * 8;
#pragma unroll
        for (int c4 = 0; c4 < 4; ++c4)
            *(uint4*)&QS(row, colb + c4 * 32) =
                *(const uint4*)(qb + (long)(q0 + row) * Q_SIZE + h * HD + colb + c4 * 32);
    }
    __syncthreads();
    short8 aq[4];
#pragma unroll
    for (int kk = 0; kk < 4; ++kk)
        aq[kk] = *(const short8*)&QS(wv * 16 + m, kk * 32 + qd * 8);

    floatx4 acc_o[8];
#pragma unroll
    for (int nb = 0; nb < 8; ++nb) acc_o[nb] = (floatx4){0.f, 0.f, 0.f, 0.f};
    float mrow[4] = {-1e30f, -1e30f, -1e30f, -1e30f};
    float lrow[4] = {0.f, 0.f, 0.f, 0.f};

    const float scale = 0.08838834764831845f;

    for (int jt = 0; jt <= qblk; ++jt) {
        const int j0 = jt * 64;
        __syncthreads();   // protect Ks/Vts (prev iter readers done)
        {   // stage K tile (64x128)
            int row = tid >> 2, colb = (tid & 3) * 8;
#pragma unroll
            for (int c4 = 0; c4 < 4; ++c4)
                *(uint4*)&KS(row, colb + c4 * 32) =
                    *(const uint4*)(kb + (long)(j0 + row) * KV_SIZE + g * HD + colb + c4 * 32);
        }
        {   // stage V^T tile (128 d-rows x 64 t-cols)
            int row = tid >> 1, colb = (tid & 1) * 8;
#pragma unroll
            for (int c4 = 0; c4 < 4; ++c4)
                *(uint4*)&VTS(row, colb + c4 * 16) =
                    *(const uint4*)(vt + ((long)g * HD + row) * T + j0 + colb + c4 * 16);
        }
        __syncthreads();

        // S = Q K^T (per wave: 16 rows x 64 cols)
        floatx4 acc_s[4];
#pragma unroll
        for (int c = 0; c < 4; ++c) acc_s[c] = (floatx4){0.f, 0.f, 0.f, 0.f};
#pragma unroll
        for (int kk = 0; kk < 4; ++kk) {
#pragma unroll
            for (int c = 0; c < 4; ++c) {
                short8 b = *(const short8*)&KS(c * 16 + m, kk * 32 + qd * 8);
                acc_s[c] = __builtin_amdgcn_mfma_f32_16x16x32_bf16(aq[kk], b, acc_s[c], 0, 0, 0);
            }
        }

        float s[4][4];
#pragma unroll
        for (int c = 0; c < 4; ++c)
#pragma unroll
            for (int r = 0; r < 4; ++r) s[c][r] = acc_s[c][r] * scale;
        if (jt == qblk) {
#pragma unroll
            for (int c = 0; c < 4; ++c)
#pragma unroll
                for (int r = 0; r < 4; ++r)
                    if (c * 16 + m > wv * 16 + qd * 4 + r) s[c][r] = -1e30f;
        }

        float alpha[4];
#pragma unroll
        for (int r = 0; r < 4; ++r) {
            float mx = fmaxf(fmaxf(s[0][r], s[1][r]), fmaxf(s[2][r], s[3][r]));
            mx = fmaxf(mx, __shfl_xor(mx, 1));
            mx = fmaxf(mx, __shfl_xor(mx, 2));
            mx = fmaxf(mx, __shfl_xor(mx, 4));
            mx = fmaxf(mx, __shfl_xor(mx, 8));
            float mnew = fmaxf(mrow[r], mx);
            alpha[r] = __expf(mrow[r] - mnew);
            mrow[r] = mnew;
        }
        float p[4][4];
#pragma unroll
        for (int c = 0; c < 4; ++c)
#pragma unroll
            for (int r = 0; r < 4; ++r) p[c][r] = __expf(s[c][r] - mrow[r]);
#pragma unroll
        for (int r = 0; r < 4; ++r) {
            float sum = p[0][r] + p[1][r] + p[2][r] + p[3][r];
            sum += __shfl_xor(sum, 1);
            sum += __shfl_xor(sum, 2);
            sum += __shfl_xor(sum, 4);
            sum += __shfl_xor(sum, 8);
            lrow[r] = lrow[r] * alpha[r] + sum;
        }
#pragma unroll
        for (int nb = 0; nb < 8; ++nb)
#pragma unroll
            for (int r = 0; r < 4; ++r) acc_o[nb][r] *= alpha[r];

        // write P to LDS (own wave region), then PV
#pragma unroll
        for (int c = 0; c < 4; ++c)
#pragma unroll
            for (int r = 0; r < 4; ++r) PS(wv, qd * 4 + r, c * 16 + m) = f2bf(p[c][r]);
        __syncthreads();

#pragma unroll
        for (int kk = 0; kk < 2; ++kk) {
            short8 pa = *(const short8*)&PS(wv, m, kk * 32 + qd * 8);
#pragma unroll
            for (int nb = 0; nb < 8; ++nb) {
                short8 vbf = *(const short8*)&VTS(nb * 16 + m, kk * 32 + qd * 8);
                acc_o[nb] = __builtin_amdgcn_mfma_f32_16x16x32_bf16(pa, vbf, acc_o[nb], 0, 0, 0);
            }
        }
    }

    // epilogue: divide by l, write bf16 to ab[t][h*128+d]
#pragma unroll
    for (int nb = 0; nb < 8; ++nb)
#pragma unroll
        for (int r = 0; r < 4; ++r)
            ab[(long)(q0 + wv * 16 + qd * 4 + r) * Q_SIZE + h * HD + nb * 16 + m] =
                f2bf(acc_o[nb][r] / lrow[r]);
}

extern "C" void kernel_launch(void* const* d_in, const int* in_sizes, int n_in,
                              void* d_out, int out_size, void* d_ws, size_t ws_size,
                              hipStream_t stream) {
    const int* positions = (const int*)d_in[0];
    const float* hidden  = (const float*)d_in[1];
    const float* w_qkv   = (const float*)d_in[2];
    const float* w_o     = (const float*)d_in[3];
    float* out = (float*)d_out;

    char* p = (char*)d_ws;
    auto alloc = [&](size_t bytes) { char* r = p; p += (bytes + 255) & ~(size_t)255; return r; };
    float* cosT = (float*)alloc((size_t)T * 64 * 4);
    float* sinT = (float*)alloc((size_t)T * 64 * 4);
    float* qkv  = (float*)alloc((size_t)T * QKV_N * 4);
    unsigned short* hb  = (unsigned short*)alloc((size_t)T * HIDDEN * 2);
    unsigned short* wqt = (unsigned short*)alloc((size_t)QKV_N * HIDDEN * 2);
    unsigned short* wot = (unsigned short*)alloc((size_t)HIDDEN * HIDDEN * 2);
    unsigned short* qb  = (unsigned short*)alloc((size_t)T * Q_SIZE * 2);
    unsigned short* kb  = (unsigned short*)alloc((size_t)T * KV_SIZE * 2);
    unsigned short* vb  = (unsigned short*)alloc((size_t)T * KV_SIZE * 2);
    unsigned short* vt  = (unsigned short*)alloc((size_t)T * KV_SIZE * 2);
    unsigned short* ab  = (unsigned short*)alloc((size_t)T * Q_SIZE * 2);

    dim3 tb(32, 8);
    prep_cossin<<<T, 64, 0, stream>>>(positions, cosT, sinT);
    convert_f32_bf16<<<(T * HIDDEN) / 1024, 256, 0, stream>>>(hidden, hb, T * HIDDEN);
    transpose_f32_bf16<<<dim3(QKV_N / 32, HIDDEN / 32), tb, 0, stream>>>(w_qkv, wqt, HIDDEN, QKV_N);
    transpose_f32_bf16<<<dim3(HIDDEN / 32, HIDDEN / 32), tb, 0, stream>>>(w_o, wot, HIDDEN, HIDDEN);
    // qkv = hidden @ w_qkv   (fp32 out)
    gemm_bt<<<dim3(T / 64, QKV_N / 64, 1), 256, 0, stream>>>(hb, 0, HIDDEN, wqt, 0, 0, HIDDEN,
                                                             qkv, 0, QKV_N, HIDDEN, 1.0f, 0);
    rope_split<<<T, 256, 0, stream>>>(qkv, cosT, sinT, qb, kb, vb);
    transpose_bf16<<<dim3(HD / 32, T / 32, NKV), tb, 0, stream>>>(vb, vt, T, HD);
    // fused causal attention -> ab (bf16, [t][h*128+d])
    flash_attn<<<dim3(32, 1, NH), 256, 0, stream>>>(qb, kb, vt, ab);
    // out = attn @ w_o  (fp32 out)
    gemm_bt<<<dim3(T / 64, HIDDEN / 64, 1), 256, 0, stream>>>(ab, 0, Q_SIZE, wot, 0, 0, HIDDEN,
                                                              out, 0, HIDDEN, Q_SIZE, 1.0f, 0);
}